// Round 1
// baseline (286.368 us; speedup 1.0000x reference)
//
#include <hip/hip_runtime.h>

typedef _Float16 f16;
typedef __attribute__((ext_vector_type(8))) _Float16 f16x8;
typedef __attribute__((ext_vector_type(4))) float f32x4;

#define NQ 65536
#define MM 2048
#define DD 256
#define LOG2E 1.44269504088896340736f

__device__ __forceinline__ void gload_lds16(const void* g, void* l) {
    __builtin_amdgcn_global_load_lds(
        (const __attribute__((address_space(1))) unsigned int*)g,
        (__attribute__((address_space(3))) unsigned int*)l,
        16, 0, 0);
}

__device__ __forceinline__ f32x4 mfma16(f16x8 a, f16x8 b, f32x4 c) {
    return __builtin_amdgcn_mfma_f32_16x16x32_f16(a, b, c, 0, 0, 0);
}

// Prep: memory f32 [2048][256] -> two fp16 copies in ws, 16B-unit layouts.
// Kprep: per 32-row tile b: unit(u,kk) = memory[32b+kk][8u..8u+7]   (u=0..31, kk=0..31)
// VTprep: per 32-row tile b: unit(u,d)  = memory[32b+8u+e][d] e=0..7 (u=0..3,  d=0..255)
__global__ void prep_kernel(const float* __restrict__ mem,
                            f16* __restrict__ kprep, f16* __restrict__ vtprep) {
    int t = blockIdx.x * blockDim.x + threadIdx.x;  // 131072 threads, 1 unit each
    if (t < 65536) {
        int b = t >> 10, r = t & 1023, u = r >> 5, kk = r & 31;
        const float* src = mem + (b * 32 + kk) * DD + u * 8;
        f16 o8[8];
#pragma unroll
        for (int e = 0; e < 8; ++e) o8[e] = (f16)src[e];
        *(f16x8*)(kprep + (size_t)t * 8) = *(f16x8*)o8;
    } else {
        int t2 = t - 65536;
        int b = t2 >> 10, r = t2 & 1023, u = r >> 8, d = r & 255;
        f16 o8[8];
#pragma unroll
        for (int e = 0; e < 8; ++e) o8[e] = (f16)mem[(b * 32 + u * 8 + e) * DD + d];
        *(f16x8*)(vtprep + (size_t)t2 * 8) = *(f16x8*)o8;
    }
}

// Main: 256 blocks x 512 threads. Wave w owns 32 q-rows. KV tile = 32, 64 iters.
__launch_bounds__(512, 2)
__global__ void attn_kernel(const float* __restrict__ q,
                            const f16* __restrict__ kprep,
                            const f16* __restrict__ vtprep,
                            float* __restrict__ out) {
    __shared__ f16 klds[8192];    // 16KB: K tile, unit layout [u=32][k=32]
    __shared__ f16 vtlds[8192];   // 16KB: VT tile, unit layout [u=4][d=256]
    __shared__ f16 plds[10240];   // 20KB: per wave [q=32][k=32 +8 pad]

    const int tid = threadIdx.x;
    const int w = __builtin_amdgcn_readfirstlane(tid >> 6);
    const int lane = tid & 63;
    const int g = (lane >> 4) & 3;
    const int l15 = lane & 15;
    const int q0 = blockIdx.x * 256 + w * 32;

    // Hoist Q fragments: frag[qs][dc]: lane holds Q[q0+16qs+l15][32dc+8g+j], j=0..7
    f16x8 qf[2][8];
#pragma unroll
    for (int qs = 0; qs < 2; ++qs)
#pragma unroll
        for (int dc = 0; dc < 8; ++dc) {
            const float* src = q + (size_t)(q0 + qs * 16 + l15) * DD + dc * 32 + g * 8;
            float4 a = *(const float4*)src;
            float4 b2 = *(const float4*)(src + 4);
            f16 t8[8] = {(f16)a.x, (f16)a.y, (f16)a.z, (f16)a.w,
                         (f16)b2.x, (f16)b2.y, (f16)b2.z, (f16)b2.w};
            qf[qs][dc] = *(f16x8*)t8;
        }

    f32x4 o[2][16];
#pragma unroll
    for (int qs = 0; qs < 2; ++qs)
#pragma unroll
        for (int dt = 0; dt < 16; ++dt) o[qs][dt] = (f32x4){0.f, 0.f, 0.f, 0.f};
    float mrow[8], lrow[8];
#pragma unroll
    for (int i = 0; i < 8; ++i) { mrow[i] = -1e30f; lrow[i] = 0.f; }

    f16* pw = plds + w * 1280;  // 32 rows * 40 f16

    for (int b = 0; b < 64; ++b) {
        // ---- stage K tile (16KB) + VT tile (16KB), linear global_load_lds
        const f16* ksrc = kprep + (size_t)b * 8192;
        const f16* vsrc = vtprep + (size_t)b * 8192;
#pragma unroll
        for (int is = 0; is < 2; ++is) {
            gload_lds16(ksrc + is * 4096 + tid * 8, klds + is * 4096 + w * 512);
            gload_lds16(vsrc + is * 4096 + tid * 8, vtlds + is * 4096 + w * 512);
        }
        __syncthreads();

        // ---- S = Q K^T  (32q x 32k), C layout: col k=l15, row q=(g)*4+rr
        f32x4 s[2][2];
#pragma unroll
        for (int qs = 0; qs < 2; ++qs)
#pragma unroll
            for (int kt = 0; kt < 2; ++kt) s[qs][kt] = (f32x4){0.f, 0.f, 0.f, 0.f};
#pragma unroll
        for (int dc = 0; dc < 8; ++dc) {
            f16x8 bk0 = *(const f16x8*)(klds + (((4 * dc + g) * 32) + l15) * 8);
            f16x8 bk1 = *(const f16x8*)(klds + (((4 * dc + g) * 32) + 16 + l15) * 8);
            s[0][0] = mfma16(qf[0][dc], bk0, s[0][0]);
            s[0][1] = mfma16(qf[0][dc], bk1, s[0][1]);
            s[1][0] = mfma16(qf[1][dc], bk0, s[1][0]);
            s[1][1] = mfma16(qf[1][dc], bk1, s[1][1]);
        }

        // ---- online softmax (base-2 domain), write P to per-wave LDS
#pragma unroll
        for (int qs = 0; qs < 2; ++qs)
#pragma unroll
            for (int rr = 0; rr < 4; ++rr) {
                const int ri = qs * 4 + rr;
                float v0 = fmaxf(s[qs][0][rr], s[qs][1][rr]) * LOG2E;
                v0 = fmaxf(v0, __shfl_xor(v0, 1));
                v0 = fmaxf(v0, __shfl_xor(v0, 2));
                v0 = fmaxf(v0, __shfl_xor(v0, 4));
                v0 = fmaxf(v0, __shfl_xor(v0, 8));
                const float mnew = fmaxf(mrow[ri], v0);
                const float fct = __builtin_amdgcn_exp2f(mrow[ri] - mnew);
                mrow[ri] = mnew;
                const float p0 = __builtin_amdgcn_exp2f(__builtin_fmaf(s[qs][0][rr], LOG2E, -mnew));
                const float p1 = __builtin_amdgcn_exp2f(__builtin_fmaf(s[qs][1][rr], LOG2E, -mnew));
                float rs = p0 + p1;
                rs += __shfl_xor(rs, 1);
                rs += __shfl_xor(rs, 2);
                rs += __shfl_xor(rs, 4);
                rs += __shfl_xor(rs, 8);
                lrow[ri] = lrow[ri] * fct + rs;
#pragma unroll
                for (int dt = 0; dt < 16; ++dt) o[qs][dt][rr] *= fct;
                const int qrow = qs * 16 + g * 4 + rr;
                pw[qrow * 40 + l15] = (f16)p0;
                pw[qrow * 40 + 16 + l15] = (f16)p1;
            }

        // ---- O += P V   (A = P from LDS, B = VT units)
        f16x8 pa0 = *(const f16x8*)(pw + l15 * 40 + g * 8);
        f16x8 pa1 = *(const f16x8*)(pw + (16 + l15) * 40 + g * 8);
#pragma unroll
        for (int dt = 0; dt < 16; ++dt) {
            f16x8 bv = *(const f16x8*)(vtlds + (g * 256 + dt * 16 + l15) * 8);
            o[0][dt] = mfma16(pa0, bv, o[0][dt]);
            o[1][dt] = mfma16(pa1, bv, o[1][dt]);
        }
        __syncthreads();
    }

    // ---- epilogue: normalize and store
#pragma unroll
    for (int qs = 0; qs < 2; ++qs)
#pragma unroll
        for (int rr = 0; rr < 4; ++rr) {
            const float inv = 1.0f / lrow[qs * 4 + rr];
            const int row = q0 + qs * 16 + g * 4 + rr;
#pragma unroll
            for (int dt = 0; dt < 16; ++dt)
                out[(size_t)row * DD + dt * 16 + l15] = o[qs][dt][rr] * inv;
        }
}

extern "C" void kernel_launch(void* const* d_in, const int* in_sizes, int n_in,
                              void* d_out, int out_size, void* d_ws, size_t ws_size,
                              hipStream_t stream) {
    const float* memory = (const float*)d_in[0];
    const float* query = (const float*)d_in[1];
    float* out = (float*)d_out;
    f16* kprep = (f16*)d_ws;                       // 1 MB
    f16* vtprep = kprep + (size_t)MM * DD;         // 1 MB
    prep_kernel<<<512, 256, 0, stream>>>(memory, kprep, vtprep);
    attn_kernel<<<256, 512, 0, stream>>>(query, kprep, vtprep, out);
}

// Round 2
// 160.891 us; speedup vs baseline: 1.7799x; 1.7799x over previous
//
#include <hip/hip_runtime.h>

typedef _Float16 f16;
typedef __attribute__((ext_vector_type(2))) _Float16 f16x2;
typedef __attribute__((ext_vector_type(8))) _Float16 f16x8;
typedef __attribute__((ext_vector_type(4))) float f32x4;

#define MM 2048
#define DD 256
#define LOG2E 1.44269504088896340736f

__device__ __forceinline__ void gload_lds16(const void* g, void* l) {
    __builtin_amdgcn_global_load_lds(
        (const __attribute__((address_space(1))) unsigned int*)g,
        (__attribute__((address_space(3))) unsigned int*)l,
        16, 0, 0);
}

__device__ __forceinline__ f32x4 mfma16(f16x8 a, f16x8 b, f32x4 c) {
    return __builtin_amdgcn_mfma_f32_16x16x32_f16(a, b, c, 0, 0, 0);
}

// Prep: memory f32 [2048][256] -> two fp16 copies in ws, 16B-unit layouts.
// Kprep: per 32-row tile b: unit(u,kk) = memory[32b+kk][8u..8u+7]   (u=0..31, kk=0..31)
// VTprep: per 32-row tile b: unit(u,d)  = memory[32b+8u+e][d] e=0..7 (u=0..3,  d=0..255)
__global__ void prep_kernel(const float* __restrict__ mem,
                            f16* __restrict__ kprep, f16* __restrict__ vtprep) {
    int t = blockIdx.x * blockDim.x + threadIdx.x;
    if (t < 65536) {
        int b = t >> 10, r = t & 1023, u = r >> 5, kk = r & 31;
        const float* src = mem + (b * 32 + kk) * DD + u * 8;
        f16 o8[8];
#pragma unroll
        for (int e = 0; e < 8; ++e) o8[e] = (f16)src[e];
        *(f16x8*)(kprep + (size_t)t * 8) = *(f16x8*)o8;
    } else {
        int t2 = t - 65536;
        int b = t2 >> 10, r = t2 & 1023, u = r >> 8, d = r & 255;
        f16 o8[8];
#pragma unroll
        for (int e = 0; e < 8; ++e) o8[e] = (f16)mem[(b * 32 + u * 8 + e) * DD + d];
        *(f16x8*)(vtprep + (size_t)t2 * 8) = *(f16x8*)o8;
    }
}

// 512 blocks x 256 threads (4 waves). Wave owns 32 q-rows. KV tile = 32, 64 iters.
// Swapped QK^T (S[k][q], q lane-local) + defer-max + double-buffered K/V staging,
// one barrier per iteration.
__launch_bounds__(256, 2)
__global__ void attn_kernel(const float* __restrict__ q,
                            const f16* __restrict__ kprep,
                            const f16* __restrict__ vtprep,
                            float* __restrict__ out) {
    __shared__ f16 klds[2][8192];    // 32KB: K tiles, unit layout [u=32][k=32]
    __shared__ f16 vtlds[2][8192];   // 32KB: VT tiles, unit layout [u=4][d=256]
    __shared__ f16 plds[4][1280];    // 10KB: per wave [q=32][k=32 +8 pad]
    __shared__ float fctlds[4][32];  // per-wave rescale/norm broadcast

    const int tid = threadIdx.x;
    const int w = __builtin_amdgcn_readfirstlane(tid >> 6);
    const int lane = tid & 63;
    const int g = lane >> 4;
    const int l15 = lane & 15;
    const int q0 = blockIdx.x * 128 + w * 32;

    // Hoist Q fragments: qf[qs][dc]: lane holds Q[q0+16qs+l15][32dc+8g+j], j=0..7
    f16x8 qf[2][8];
#pragma unroll
    for (int qs = 0; qs < 2; ++qs)
#pragma unroll
        for (int dc = 0; dc < 8; ++dc) {
            const float* src = q + (size_t)(q0 + qs * 16 + l15) * DD + dc * 32 + g * 8;
            float4 a = *(const float4*)src;
            float4 b2 = *(const float4*)(src + 4);
            f16 t8[8] = {(f16)a.x, (f16)a.y, (f16)a.z, (f16)a.w,
                         (f16)b2.x, (f16)b2.y, (f16)b2.z, (f16)b2.w};
            qf[qs][dc] = *(f16x8*)t8;
        }

    f32x4 o[2][16];
#pragma unroll
    for (int qs = 0; qs < 2; ++qs)
#pragma unroll
        for (int dt = 0; dt < 16; ++dt) o[qs][dt] = (f32x4){0.f, 0.f, 0.f, 0.f};
    float m[2] = {-1e30f, -1e30f};
    float l[2] = {0.f, 0.f};

    f16* pw = plds[w];

#define STAGE(b_, c_)                                                              \
    do {                                                                           \
        const f16* ks_ = kprep + (size_t)(b_)*8192;                                \
        const f16* vs_ = vtprep + (size_t)(b_)*8192;                               \
        _Pragma("unroll")                                                          \
        for (int i_ = 0; i_ < 4; ++i_) {                                           \
            gload_lds16(ks_ + i_ * 2048 + w * 512 + lane * 8,                      \
                        &klds[c_][i_ * 2048 + w * 512]);                           \
            gload_lds16(vs_ + i_ * 2048 + w * 512 + lane * 8,                      \
                        &vtlds[c_][i_ * 2048 + w * 512]);                          \
        }                                                                          \
    } while (0)

    STAGE(0, 0);

    for (int b = 0; b < 64; ++b) {
        const int c = b & 1;
        __syncthreads();  // buf[c] staged (vmcnt drained) + prev readers of buf[c^1] done
        if (b < 63) STAGE(b + 1, c ^ 1);

        // ---- S^T = K Q^T: lane (g,l15) reg rr of s[qs][kt] = S[k=16kt+4g+rr][q=qs*16+l15]
        f32x4 s[2][2];
#pragma unroll
        for (int qs = 0; qs < 2; ++qs)
#pragma unroll
            for (int kt = 0; kt < 2; ++kt) s[qs][kt] = (f32x4){0.f, 0.f, 0.f, 0.f};
#pragma unroll
        for (int dc = 0; dc < 8; ++dc) {
            f16x8 bk0 = *(const f16x8*)(&klds[c][(((dc * 4 + g) * 32) + l15) * 8]);
            f16x8 bk1 = *(const f16x8*)(&klds[c][(((dc * 4 + g) * 32) + 16 + l15) * 8]);
            s[0][0] = mfma16(bk0, qf[0][dc], s[0][0]);
            s[0][1] = mfma16(bk1, qf[0][dc], s[0][1]);
            s[1][0] = mfma16(bk0, qf[1][dc], s[1][0]);
            s[1][1] = mfma16(bk1, qf[1][dc], s[1][1]);
        }

        // ---- online softmax, in-register (q = l15, replicated across g)
#pragma unroll
        for (int qs = 0; qs < 2; ++qs) {
            float a0 = fmaxf(fmaxf(s[qs][0][0], s[qs][0][1]), fmaxf(s[qs][0][2], s[qs][0][3]));
            float a1 = fmaxf(fmaxf(s[qs][1][0], s[qs][1][1]), fmaxf(s[qs][1][2], s[qs][1][3]));
            float sm = fmaxf(a0, a1) * LOG2E;
            sm = fmaxf(sm, __shfl_xor(sm, 16));
            sm = fmaxf(sm, __shfl_xor(sm, 32));
            if (__any(sm > m[qs] + 8.0f)) {  // defer-max: rescale only on real growth
                const float mnew = fmaxf(m[qs], sm);
                const float fct = __builtin_amdgcn_exp2f(m[qs] - mnew);
                m[qs] = mnew;
                l[qs] *= fct;
                if (lane < 16) fctlds[w][qs * 16 + lane] = fct;
                const float f0 = fctlds[w][qs * 16 + 4 * g + 0];
                const float f1 = fctlds[w][qs * 16 + 4 * g + 1];
                const float f2 = fctlds[w][qs * 16 + 4 * g + 2];
                const float f3 = fctlds[w][qs * 16 + 4 * g + 3];
#pragma unroll
                for (int dt = 0; dt < 16; ++dt) {
                    o[qs][dt][0] *= f0;
                    o[qs][dt][1] *= f1;
                    o[qs][dt][2] *= f2;
                    o[qs][dt][3] *= f3;
                }
            }
            float pr[2][4];
            float rs = 0.f;
#pragma unroll
            for (int kt = 0; kt < 2; ++kt)
#pragma unroll
                for (int rr = 0; rr < 4; ++rr) {
                    pr[kt][rr] = __builtin_amdgcn_exp2f(
                        __builtin_fmaf(s[qs][kt][rr], LOG2E, -m[qs]));
                    rs += pr[kt][rr];
                }
            rs += __shfl_xor(rs, 16);
            rs += __shfl_xor(rs, 32);
            l[qs] += rs;
            // pack pairs -> 4 dword LDS writes: P[q=qs*16+l15][k=16kt+4g+{0,1,2,3}]
#pragma unroll
            for (int kt = 0; kt < 2; ++kt) {
                f16x2 w0 = {(f16)pr[kt][0], (f16)pr[kt][1]};
                f16x2 w1 = {(f16)pr[kt][2], (f16)pr[kt][3]};
                *(f16x2*)(pw + (qs * 16 + l15) * 40 + kt * 16 + 4 * g) = w0;
                *(f16x2*)(pw + (qs * 16 + l15) * 40 + kt * 16 + 4 * g + 2) = w1;
            }
        }

        // ---- O += P V  (A-frag: P[q=l15][k=8g+j] from LDS; B-frag: VT units)
        f16x8 pa0 = *(const f16x8*)(pw + l15 * 40 + g * 8);
        f16x8 pa1 = *(const f16x8*)(pw + (16 + l15) * 40 + g * 8);
#pragma unroll
        for (int dt = 0; dt < 16; ++dt) {
            f16x8 bv = *(const f16x8*)(&vtlds[c][(g * 256 + dt * 16 + l15) * 8]);
            o[0][dt] = mfma16(pa0, bv, o[0][dt]);
            o[1][dt] = mfma16(pa1, bv, o[1][dt]);
        }
    }

    // ---- epilogue: broadcast 1/l by q-row, normalize, store
    if (lane < 16) {
        fctlds[w][lane] = 1.0f / l[0];
        fctlds[w][16 + lane] = 1.0f / l[1];
    }
#pragma unroll
    for (int qs = 0; qs < 2; ++qs) {
        const float i0 = fctlds[w][qs * 16 + 4 * g + 0];
        const float i1 = fctlds[w][qs * 16 + 4 * g + 1];
        const float i2 = fctlds[w][qs * 16 + 4 * g + 2];
        const float i3 = fctlds[w][qs * 16 + 4 * g + 3];
#pragma unroll
        for (int dt = 0; dt < 16; ++dt) {
            const size_t base = (size_t)(q0 + qs * 16 + 4 * g) * DD + dt * 16 + l15;
            out[base] = o[qs][dt][0] * i0;
            out[base + DD] = o[qs][dt][1] * i1;
            out[base + 2 * DD] = o[qs][dt][2] * i2;
            out[base + 3 * DD] = o[qs][dt][3] * i3;
        }
    }
}

extern "C" void kernel_launch(void* const* d_in, const int* in_sizes, int n_in,
                              void* d_out, int out_size, void* d_ws, size_t ws_size,
                              hipStream_t stream) {
    const float* memory = (const float*)d_in[0];
    const float* query = (const float*)d_in[1];
    float* out = (float*)d_out;
    f16* kprep = (f16*)d_ws;                 // 1 MB
    f16* vtprep = kprep + (size_t)MM * DD;   // 1 MB
    prep_kernel<<<512, 256, 0, stream>>>(memory, kprep, vtprep);
    attn_kernel<<<512, 256, 0, stream>>>(query, kprep, vtprep, out);
}